// Round 1
// baseline (167.378 us; speedup 1.0000x reference)
//
#include <hip/hip_runtime.h>

// Problem: Q=32, S=25, L=64, F=256, H=64
// out[q,s,i,f] = sum_j softmax_j( sum_h tanh(Wq[q,i,h]*Wh[s,j,h]) ) * hs[s,j,f]
// Wq = qs @ W^T + b  (pre-scaled by 2*log2e so exp2 arg is ready)
// Wh = hs @ W^T + b

#define NQ 32
#define NS 25
#define NL 64
#define NF 256
#define NH 64

__device__ __constant__ const float K2LOG2E = 2.8853900817779268f; // 2*log2(e)
#define C_LOG2E 1.4426950408889634f

// ---------------- projection kernel ----------------
// 3648 rows total: rows 0..2047 from qs -> Wqs (scaled), 2048..3647 from hs -> Whs.
// 16 rows/block, 228 blocks, 256 threads.
__global__ __launch_bounds__(256) void proj_kernel(
    const float* __restrict__ qs, const float* __restrict__ hs,
    const float* __restrict__ W, const float* __restrict__ b,
    float* __restrict__ Wqs, float* __restrict__ Whs)
{
    __shared__ float rows[16 * 256];
    const int t  = threadIdx.x;
    const int r0 = blockIdx.x * 16;
    const bool is_q = (r0 < 2048);
    const float* src = is_q ? (qs + (size_t)r0 * 256) : (hs + (size_t)(r0 - 2048) * 256);

    // stage 16 input rows (coalesced float4)
    const float4* s4 = (const float4*)src;
    float4* l4 = (float4*)rows;
#pragma unroll
    for (int k = 0; k < 4; ++k) l4[t + 256 * k] = s4[t + 256 * k];
    __syncthreads();

    const int h  = t & 63;   // head dim
    const int rg = t >> 6;   // 0..3 row group
    float acc0 = 0.f, acc1 = 0.f, acc2 = 0.f, acc3 = 0.f;
    const float4* w4 = (const float4*)(W + h * 256);
#pragma unroll 8
    for (int f4 = 0; f4 < 64; ++f4) {
        float4 wv = w4[f4];
        float4 x0 = *((const float4*)&rows[(rg + 0) * 256] + f4);
        float4 x1 = *((const float4*)&rows[(rg + 4) * 256] + f4);
        float4 x2 = *((const float4*)&rows[(rg + 8) * 256] + f4);
        float4 x3 = *((const float4*)&rows[(rg + 12) * 256] + f4);
        acc0 += x0.x * wv.x + x0.y * wv.y + x0.z * wv.z + x0.w * wv.w;
        acc1 += x1.x * wv.x + x1.y * wv.y + x1.z * wv.z + x1.w * wv.w;
        acc2 += x2.x * wv.x + x2.y * wv.y + x2.z * wv.z + x2.w * wv.w;
        acc3 += x3.x * wv.x + x3.y * wv.y + x3.z * wv.z + x3.w * wv.w;
    }
    const float bias = b[h];
    float v0 = acc0 + bias, v1 = acc1 + bias, v2 = acc2 + bias, v3 = acc3 + bias;
    if (is_q) { v0 *= K2LOG2E; v1 *= K2LOG2E; v2 *= K2LOG2E; v3 *= K2LOG2E; }
    float* dst = is_q ? (Wqs + (size_t)r0 * 64) : (Whs + (size_t)(r0 - 2048) * 64);
    dst[(rg + 0)  * 64 + h] = v0;
    dst[(rg + 4)  * 64 + h] = v1;
    dst[(rg + 8)  * 64 + h] = v2;
    dst[(rg + 12) * 64 + h] = v3;
}

// ---------------- fused attention kernel ----------------
// One block per (q,s). 256 threads.
#define ASTRIDE 68   // [h][i] tiles, padded: b128-aligned, conflict-free
#define SSTRIDE 65   // scores [i][j], padded

__global__ __launch_bounds__(256) void attn_kernel(
    const float* __restrict__ Wqs, const float* __restrict__ Whs,
    const float* __restrict__ hs, float* __restrict__ out)
{
    __shared__ float smem[2 * 64 * ASTRIDE];  // 8704 floats = 34 KB
    float* Alds = smem;                 // Wq[q] transposed [h][i], pre-scaled
    float* Blds = smem + 64 * ASTRIDE;  // Wh[s] transposed [h][j]
    float* Sc   = smem;                 // scores/att [i][j] stride 65 (overlaps A)

    const int t   = threadIdx.x;
    const int bid = blockIdx.x;
    const int q = bid / NS;
    const int s = bid % NS;

    // ---- stage A,B transposed into LDS ----
    {
        const float4* a4 = (const float4*)(Wqs + (size_t)q * NL * NH);
        const float4* b4 = (const float4*)(Whs + (size_t)s * NL * NH);
#pragma unroll
        for (int k = 0; k < 4; ++k) {
            const int idx4 = t + 256 * k;
            const int i  = idx4 >> 4;          // row
            const int h0 = (idx4 & 15) << 2;   // 4 consecutive h
            float4 va = a4[idx4];
            float4 vb = b4[idx4];
            Alds[(h0 + 0) * ASTRIDE + i] = va.x;
            Alds[(h0 + 1) * ASTRIDE + i] = va.y;
            Alds[(h0 + 2) * ASTRIDE + i] = va.z;
            Alds[(h0 + 3) * ASTRIDE + i] = va.w;
            Blds[(h0 + 0) * ASTRIDE + i] = vb.x;
            Blds[(h0 + 1) * ASTRIDE + i] = vb.y;
            Blds[(h0 + 2) * ASTRIDE + i] = vb.z;
            Blds[(h0 + 3) * ASTRIDE + i] = vb.w;
        }
    }
    __syncthreads();

    // ---- phase 1: scores, 4x4 tile per thread ----
    const int i0 = (t >> 4) << 2;
    const int j0 = (t & 15) << 2;
    float sum[4][4];
#pragma unroll
    for (int ii = 0; ii < 4; ++ii)
#pragma unroll
        for (int jj = 0; jj < 4; ++jj) sum[ii][jj] = 0.f;

#pragma unroll 2
    for (int h = 0; h < 64; ++h) {
        float4 av = *(const float4*)&Alds[h * ASTRIDE + i0];
        float4 bv = *(const float4*)&Blds[h * ASTRIDE + j0];
        float aa[4] = {av.x, av.y, av.z, av.w};
        float bb[4] = {bv.x, bv.y, bv.z, bv.w};
#pragma unroll
        for (int ii = 0; ii < 4; ++ii) {
#pragma unroll
            for (int jj = 0; jj < 4; ++jj) {
                // tanh(x) = 1 - 2/(1+exp2(K2LOG2E*x)); A is pre-scaled
                float x  = aa[ii] * bb[jj];
                float e  = __builtin_amdgcn_exp2f(x);
                float r  = __builtin_amdgcn_rcpf(1.f + e);
                sum[ii][jj] += r;
            }
        }
    }
    __syncthreads();  // done reading A/B; Sc overlaps A

    // score = 64 - 2*sum; constant 64 drops under softmax -> store -2*sum
#pragma unroll
    for (int ii = 0; ii < 4; ++ii)
#pragma unroll
        for (int jj = 0; jj < 4; ++jj)
            Sc[(i0 + ii) * SSTRIDE + (j0 + jj)] = -2.f * sum[ii][jj];
    __syncthreads();

    // ---- softmax over j (4 threads per row, quad shuffle reduce) ----
    {
        const int i = t >> 2;
        const int c = t & 3;
        float* row = &Sc[i * SSTRIDE + c * 16];
        float v[16];
        float m = -1e30f;
#pragma unroll
        for (int k = 0; k < 16; ++k) { v[k] = row[k]; m = fmaxf(m, v[k]); }
        m = fmaxf(m, __shfl_xor(m, 1));
        m = fmaxf(m, __shfl_xor(m, 2));
        float d = 0.f;
#pragma unroll
        for (int k = 0; k < 16; ++k) {
            float p = __builtin_amdgcn_exp2f((v[k] - m) * C_LOG2E);
            v[k] = p; d += p;
        }
        d += __shfl_xor(d, 1);
        d += __shfl_xor(d, 2);
        const float inv = __builtin_amdgcn_rcpf(d);
#pragma unroll
        for (int k = 0; k < 16; ++k) row[k] = v[k] * inv;
    }
    __syncthreads();

    // ---- PV: out[i][f] = sum_j att[i][j]*hs[s][j][f] ----
    // thread: c = f-group (16 floats), ig + 16m = rows
    const int c  = t & 15;
    const int ig = t >> 4;
    const int fbase = c * 16;
    const float* hsS = hs + (size_t)s * NL * NF;

    float4 acc[4][4];
#pragma unroll
    for (int m = 0; m < 4; ++m)
#pragma unroll
        for (int kk = 0; kk < 4; ++kk) acc[m][kk] = make_float4(0.f, 0.f, 0.f, 0.f);

#pragma unroll 2
    for (int j = 0; j < 64; ++j) {
        const float4* hrow = (const float4*)(hsS + j * NF + fbase);
        float4 h0 = hrow[0], h1 = hrow[1], h2 = hrow[2], h3 = hrow[3];
#pragma unroll
        for (int m = 0; m < 4; ++m) {
            float a = Sc[(ig + 16 * m) * SSTRIDE + j];
            acc[m][0].x = fmaf(a, h0.x, acc[m][0].x); acc[m][0].y = fmaf(a, h0.y, acc[m][0].y);
            acc[m][0].z = fmaf(a, h0.z, acc[m][0].z); acc[m][0].w = fmaf(a, h0.w, acc[m][0].w);
            acc[m][1].x = fmaf(a, h1.x, acc[m][1].x); acc[m][1].y = fmaf(a, h1.y, acc[m][1].y);
            acc[m][1].z = fmaf(a, h1.z, acc[m][1].z); acc[m][1].w = fmaf(a, h1.w, acc[m][1].w);
            acc[m][2].x = fmaf(a, h2.x, acc[m][2].x); acc[m][2].y = fmaf(a, h2.y, acc[m][2].y);
            acc[m][2].z = fmaf(a, h2.z, acc[m][2].z); acc[m][2].w = fmaf(a, h2.w, acc[m][2].w);
            acc[m][3].x = fmaf(a, h3.x, acc[m][3].x); acc[m][3].y = fmaf(a, h3.y, acc[m][3].y);
            acc[m][3].z = fmaf(a, h3.z, acc[m][3].z); acc[m][3].w = fmaf(a, h3.w, acc[m][3].w);
        }
    }

    float* outp = out + ((size_t)(q * NS + s) * NL) * NF;
#pragma unroll
    for (int m = 0; m < 4; ++m) {
        float* orow = outp + (ig + 16 * m) * NF + fbase;
#pragma unroll
        for (int kk = 0; kk < 4; ++kk)
            *(float4*)(orow + kk * 4) = acc[m][kk];
    }
}

extern "C" void kernel_launch(void* const* d_in, const int* in_sizes, int n_in,
                              void* d_out, int out_size, void* d_ws, size_t ws_size,
                              hipStream_t stream) {
    const float* qs = (const float*)d_in[0];
    const float* hs = (const float*)d_in[1];
    const float* W  = (const float*)d_in[2];
    const float* b  = (const float*)d_in[3];
    float* out = (float*)d_out;

    float* Wqs = (float*)d_ws;               // 32*64*64  = 131072 floats (scaled)
    float* Whs = Wqs + NQ * NL * NH;         // 25*64*64  = 102400 floats

    proj_kernel<<<228, 256, 0, stream>>>(qs, hs, W, b, Wqs, Whs);
    attn_kernel<<<NQ * NS, 256, 0, stream>>>(Wqs, Whs, hs, out);
}